// Round 1
// baseline (551.755 us; speedup 1.0000x reference)
//
#include <hip/hip_runtime.h>
#include <hip/hip_fp16.h>
#include <stdint.h>

#define FP8_MAX_V 448.0f
#define BM 128
#define BN 128
#define BKB 64   // K-bytes per tile step (fp8 => 64 elements)

typedef float floatx4 __attribute__((ext_vector_type(4)));

// Deterministic bf16 round-to-nearest-even of an fp32 value, returned widened to fp32.
__device__ __forceinline__ float bf16_rne(float v) {
  uint32_t u = __float_as_uint(v);
  u = (u + 0x7fffu + ((u >> 16) & 1u)) & 0xffff0000u;
  return __uint_as_float(u);
}

// Pack 4 fp32 (already clipped to +-448) into 4 OCP e4m3fn bytes via HW RNE cvt.
__device__ __forceinline__ uint32_t pack4_fp8(float a, float b, float c, float d) {
  int p = 0;
  p = __builtin_amdgcn_cvt_pk_fp8_f32(a, b, p, false);  // bytes 0..1
  p = __builtin_amdgcn_cvt_pk_fp8_f32(c, d, p, true);   // bytes 2..3
  return (uint32_t)p;
}

__device__ __forceinline__ void gload_lds16(const uint8_t* g, uint8_t* l) {
  __builtin_amdgcn_global_load_lds(
      (const __attribute__((address_space(1))) uint32_t*)g,
      (__attribute__((address_space(3))) uint32_t*)l,
      16, 0, 0);
}

// Per-row quantization: amax over K -> scale -> fp8. FP16RT: fp16 round-trip the
// scale (weight path, matches reference's scale.astype(fp16).astype(fp32)).
template <bool FP16RT>
__global__ __launch_bounds__(256) void quant_rows_kernel(
    const float* __restrict__ in, uint8_t* __restrict__ out8,
    float* __restrict__ scales, int K) {
  const int row = blockIdx.x;
  const int tid = threadIdx.x;
  const float* rp = in + (size_t)row * K;

  // K = 4096: 16 floats/thread as 4x float4, coalesced (stride-256 float4s).
  float4 v[4];
  float amax = 0.f;
#pragma unroll
  for (int i = 0; i < 4; ++i) {
    v[i] = ((const float4*)rp)[i * 256 + tid];
    amax = fmaxf(amax, fmaxf(fmaxf(fabsf(v[i].x), fabsf(v[i].y)),
                             fmaxf(fabsf(v[i].z), fabsf(v[i].w))));
  }
#pragma unroll
  for (int off = 32; off; off >>= 1) amax = fmaxf(amax, __shfl_xor(amax, off));
  __shared__ float red[4];
  if ((tid & 63) == 0) red[tid >> 6] = amax;
  __syncthreads();
  amax = fmaxf(fmaxf(red[0], red[1]), fmaxf(red[2], red[3]));

  float scale = fmaxf(amax / FP8_MAX_V, 1e-6f);
  if (FP16RT) scale = __half2float(__float2half(scale));  // RNE, matches jnp fp16 round-trip
  if (tid == 0) scales[row] = scale;

  uint32_t* op = (uint32_t*)(out8 + (size_t)row * K);
#pragma unroll
  for (int i = 0; i < 4; ++i) {
    // true fp32 division (correctly rounded) to match numpy's x / scale
    float qa = fminf(fmaxf(v[i].x / scale, -FP8_MAX_V), FP8_MAX_V);
    float qb = fminf(fmaxf(v[i].y / scale, -FP8_MAX_V), FP8_MAX_V);
    float qc = fminf(fmaxf(v[i].z / scale, -FP8_MAX_V), FP8_MAX_V);
    float qd = fminf(fmaxf(v[i].w / scale, -FP8_MAX_V), FP8_MAX_V);
    op[i * 256 + tid] = pack4_fp8(qa, qb, qc, qd);
  }
}

// C[t,o] = sum_k A8[t,k]*B8[o,k]  (both K-major), scaled + bias + bf16 round.
// m97-structure: 128x128 tile, BK=64 bytes, global_load_lds width=16,
// 4 waves in 2x2, each wave 64x64 = 4x4 fragments of 16x16x32 fp8 MFMA.
__global__ __launch_bounds__(256) void gemm_fp8_kernel(
    const uint8_t* __restrict__ A8, const uint8_t* __restrict__ B8,
    const float* __restrict__ asc, const float* __restrict__ wsc,
    const float* __restrict__ bias, float* __restrict__ out,
    int M, int N, int K) {
  __shared__ __align__(16) uint8_t As[BM * BKB];  // 8 KB
  __shared__ __align__(16) uint8_t Bs[BN * BKB];  // 8 KB

  const int tid = threadIdx.x;
  const int lane = tid & 63;
  const int wid = tid >> 6;
  const int wr = wid >> 1;  // 0..1
  const int wc = wid & 1;   // 0..1

  const int ntn = N / BN;
  const int bm = blockIdx.x / ntn;
  const int bn = blockIdx.x % ntn;

  floatx4 acc[4][4] = {};

  // Staging: each thread moves 16B; rows 0..63 by (tid>>2), 16B chunk (tid&3).
  const int srow = tid >> 2;
  const int sk = (tid & 3) * 16;
  const uint8_t* ga0 = A8 + (size_t)(bm * BM + srow) * K + sk;
  const uint8_t* gb0 = B8 + (size_t)(bn * BN + srow) * K + sk;
  const size_t half = (size_t)64 * K;
  uint8_t* lA = As + tid * 16;   // wave-uniform base + lane*16 (gload_lds rule)
  uint8_t* lB = Bs + tid * 16;

  const int fr = lane & 15;        // fragment row/col within 16
  const int fk = (lane >> 4) * 8;  // fragment K byte offset within 32

  for (int k0 = 0; k0 < K; k0 += BKB) {
    __syncthreads();  // previous tile fully consumed
    gload_lds16(ga0 + k0, lA);
    gload_lds16(ga0 + half + k0, lA + 4096);
    gload_lds16(gb0 + k0, lB);
    gload_lds16(gb0 + half + k0, lB + 4096);
    __syncthreads();  // compiler drains vmcnt(0) before barrier

#pragma unroll
    for (int ks = 0; ks < 2; ++ks) {
      int64_t a[4], b[4];
#pragma unroll
      for (int m = 0; m < 4; ++m)
        a[m] = *(const int64_t*)(As + (size_t)(wr * 64 + m * 16 + fr) * BKB + ks * 32 + fk);
#pragma unroll
      for (int n = 0; n < 4; ++n)
        b[n] = *(const int64_t*)(Bs + (size_t)(wc * 64 + n * 16 + fr) * BKB + ks * 32 + fk);
#pragma unroll
      for (int m = 0; m < 4; ++m)
#pragma unroll
        for (int n = 0; n < 4; ++n)
          acc[m][n] = __builtin_amdgcn_mfma_f32_16x16x32_fp8_fp8(a[m], b[n], acc[m][n], 0, 0, 0);
    }
  }

  // Epilogue: C/D 16x16 layout col=lane&15, row=(lane>>4)*4+r (dtype-independent).
  const int rbase = bm * BM + wr * 64;
  const int cbase = bn * BN + wc * 64;
#pragma unroll
  for (int n = 0; n < 4; ++n) {
    const int col = cbase + n * 16 + fr;
    const float wv = wsc[col];
    const float bb = bf16_rne(bias[col]);  // bias.astype(bf16).astype(f32)
#pragma unroll
    for (int m = 0; m < 4; ++m) {
      const int r0 = rbase + m * 16 + (lane >> 4) * 4;
#pragma unroll
      for (int r = 0; r < 4; ++r) {
        const int row = r0 + r;
        // reference order: (acc * act_scale) * w_scale + bias_bf16, then bf16 RNE
        float v = (acc[m][n][r] * asc[row]) * wv + bb;
        out[(size_t)row * N + col] = bf16_rne(v);
      }
    }
  }
}

extern "C" void kernel_launch(void* const* d_in, const int* in_sizes, int n_in,
                              void* d_out, int out_size, void* d_ws, size_t ws_size,
                              hipStream_t stream) {
  const float* x = (const float*)d_in[0];     // [B,S,K] f32
  const float* w = (const float*)d_in[1];     // [N,K] f32
  const float* bias = (const float*)d_in[2];  // [N] f32
  float* out = (float*)d_out;                 // [M,N] f32 (bf16-rounded values)

  const int N = in_sizes[2];             // 4096 (D_OUT)
  const int K = in_sizes[1] / N;         // 4096 (D_IN)
  const int M = in_sizes[0] / K;         // 8192 tokens

  uint8_t* x8 = (uint8_t*)d_ws;                    // M*K bytes
  uint8_t* w8 = x8 + (size_t)M * K;                // N*K bytes
  float* asc = (float*)(w8 + (size_t)N * K);       // M floats
  float* wsc = asc + M;                            // N floats
  (void)ws_size; (void)n_in; (void)out_size;

  quant_rows_kernel<false><<<M, 256, 0, stream>>>(x, x8, asc, K);
  quant_rows_kernel<true><<<N, 256, 0, stream>>>(w, w8, wsc, K);
  gemm_fp8_kernel<<<(M / BM) * (N / BN), 256, 0, stream>>>(x8, w8, asc, wsc, bias, out, M, N, K);
}

// Round 2
// 435.710 us; speedup vs baseline: 1.2663x; 1.2663x over previous
//
#include <hip/hip_runtime.h>
#include <hip/hip_fp16.h>
#include <stdint.h>

#define FP8_MAX_V 448.0f
#define BM 128
#define BN 128
#define BKB 128  // K-bytes per tile step (fp8 => 128 elements); LDS row = 128 B

typedef float floatx4 __attribute__((ext_vector_type(4)));

// Deterministic bf16 round-to-nearest-even of an fp32 value, returned widened to fp32.
__device__ __forceinline__ float bf16_rne(float v) {
  uint32_t u = __float_as_uint(v);
  u = (u + 0x7fffu + ((u >> 16) & 1u)) & 0xffff0000u;
  return __uint_as_float(u);
}

// Pack 4 fp32 (already clipped to +-448) into 4 OCP e4m3fn bytes via HW RNE cvt.
__device__ __forceinline__ uint32_t pack4_fp8(float a, float b, float c, float d) {
  int p = 0;
  p = __builtin_amdgcn_cvt_pk_fp8_f32(a, b, p, false);  // bytes 0..1
  p = __builtin_amdgcn_cvt_pk_fp8_f32(c, d, p, true);   // bytes 2..3
  return (uint32_t)p;
}

__device__ __forceinline__ void gload_lds16(const uint8_t* g, uint8_t* l) {
  __builtin_amdgcn_global_load_lds(
      (const __attribute__((address_space(1))) uint32_t*)g,
      (__attribute__((address_space(3))) uint32_t*)l,
      16, 0, 0);
}

// Per-row quantization: amax over K -> scale -> fp8. FP16RT: fp16 round-trip the
// scale (weight path, matches reference's scale.astype(fp16).astype(fp32)).
template <bool FP16RT>
__global__ __launch_bounds__(256) void quant_rows_kernel(
    const float* __restrict__ in, uint8_t* __restrict__ out8,
    float* __restrict__ scales, int K) {
  const int row = blockIdx.x;
  const int tid = threadIdx.x;
  const float* rp = in + (size_t)row * K;

  // K = 4096: 16 floats/thread as 4x float4, coalesced (stride-256 float4s).
  float4 v[4];
  float amax = 0.f;
#pragma unroll
  for (int i = 0; i < 4; ++i) {
    v[i] = ((const float4*)rp)[i * 256 + tid];
    amax = fmaxf(amax, fmaxf(fmaxf(fabsf(v[i].x), fabsf(v[i].y)),
                             fmaxf(fabsf(v[i].z), fabsf(v[i].w))));
  }
#pragma unroll
  for (int off = 32; off; off >>= 1) amax = fmaxf(amax, __shfl_xor(amax, off));
  __shared__ float red[4];
  if ((tid & 63) == 0) red[tid >> 6] = amax;
  __syncthreads();
  amax = fmaxf(fmaxf(red[0], red[1]), fmaxf(red[2], red[3]));

  float scale = fmaxf(amax / FP8_MAX_V, 1e-6f);
  if (FP16RT) scale = __half2float(__float2half(scale));  // RNE, matches jnp fp16 round-trip
  if (tid == 0) scales[row] = scale;

  uint32_t* op = (uint32_t*)(out8 + (size_t)row * K);
#pragma unroll
  for (int i = 0; i < 4; ++i) {
    // true fp32 division (correctly rounded) to match numpy's x / scale
    float qa = fminf(fmaxf(v[i].x / scale, -FP8_MAX_V), FP8_MAX_V);
    float qb = fminf(fmaxf(v[i].y / scale, -FP8_MAX_V), FP8_MAX_V);
    float qc = fminf(fmaxf(v[i].z / scale, -FP8_MAX_V), FP8_MAX_V);
    float qd = fminf(fmaxf(v[i].w / scale, -FP8_MAX_V), FP8_MAX_V);
    op[i * 256 + tid] = pack4_fp8(qa, qb, qc, qd);
  }
}

// C[t,o] = sum_k A8[t,k]*B8[o,k]  (both K-major), scaled + bias + bf16 round.
// 128x128 tile, BKB=128 bytes, global_load_lds width=16, 4 waves in 2x2,
// each wave 64x64 = 4x4 fragments of 16x16x32 fp8 MFMA, 4 K-steps per tile.
//
// LDS swizzle (T2, rule #21 both-sides): 16B chunk index c16 within each
// 128B row is XOR'd with (row&7). Staging keeps LDS dest linear (gload_lds
// requirement) and pre-swizzles the per-lane GLOBAL source; reads apply the
// same XOR. Bank spread: (4*(c16^(fr&7)) + 2b) mod 32 -> 2-way (free).
__global__ __launch_bounds__(256) void gemm_fp8_kernel(
    const uint8_t* __restrict__ A8, const uint8_t* __restrict__ B8,
    const float* __restrict__ asc, const float* __restrict__ wsc,
    const float* __restrict__ bias, float* __restrict__ out,
    int M, int N, int K) {
  __shared__ __align__(16) uint8_t As[BM * BKB];  // 16 KB
  __shared__ __align__(16) uint8_t Bs[BN * BKB];  // 16 KB

  const int tid = threadIdx.x;
  const int lane = tid & 63;
  const int wid = tid >> 6;
  const int wr = wid >> 1;  // 0..1
  const int wc = wid & 1;   // 0..1

  const int ntn = N / BN;
  const int bm = blockIdx.x / ntn;
  const int bn = blockIdx.x % ntn;

  floatx4 acc[4][4] = {};

  // Staging: thread tid -> LDS linear offset tid*16 (row=tid>>3, c16_phys=tid&7),
  // global source chunk = c16_phys ^ (row&7). Row stride 32 between the 4 calls
  // preserves (row&7), so one source offset serves all calls.
  const int srow = tid >> 3;                      // 0..31
  const int sc_log = (tid & 7) ^ (srow & 7);      // pre-swizzled source chunk
  const uint8_t* ga0 = A8 + (size_t)(bm * BM + srow) * K + sc_log * 16;
  const uint8_t* gb0 = B8 + (size_t)(bn * BN + srow) * K + sc_log * 16;
  const size_t rstep = (size_t)32 * K;
  uint8_t* lA = As + tid * 16;
  uint8_t* lB = Bs + tid * 16;

  const int fr = lane & 15;        // fragment row/col within 16
  const int hi = lane >> 4;        // K sub-chunk selector
  const int bofs = (hi & 1) * 8;   // byte offset within 16B chunk
  const int hb = hi >> 1;
  const int fsw = fr & 7;          // read-side swizzle key

  for (int k0 = 0; k0 < K; k0 += BKB) {
    __syncthreads();  // previous tile fully consumed
#pragma unroll
    for (int i = 0; i < 4; ++i) gload_lds16(ga0 + i * rstep + k0, lA + i * 4096);
#pragma unroll
    for (int i = 0; i < 4; ++i) gload_lds16(gb0 + i * rstep + k0, lB + i * 4096);
    __syncthreads();  // compiler drains vmcnt(0) before barrier

#pragma unroll
    for (int ks = 0; ks < 4; ++ks) {
      const int koff = ((ks * 2 + hb) ^ fsw) * 16 + bofs;  // swizzled read offset
      int64_t a[4], b[4];
#pragma unroll
      for (int m = 0; m < 4; ++m)
        a[m] = *(const int64_t*)(As + (size_t)(wr * 64 + m * 16 + fr) * BKB + koff);
#pragma unroll
      for (int n = 0; n < 4; ++n)
        b[n] = *(const int64_t*)(Bs + (size_t)(wc * 64 + n * 16 + fr) * BKB + koff);
#pragma unroll
      for (int m = 0; m < 4; ++m)
#pragma unroll
        for (int n = 0; n < 4; ++n)
          acc[m][n] = __builtin_amdgcn_mfma_f32_16x16x32_fp8_fp8(a[m], b[n], acc[m][n], 0, 0, 0);
    }
  }

  // Epilogue: C/D 16x16 layout col=lane&15, row=(lane>>4)*4+r (dtype-independent).
  const int rbase = bm * BM + wr * 64;
  const int cbase = bn * BN + wc * 64;
#pragma unroll
  for (int n = 0; n < 4; ++n) {
    const int col = cbase + n * 16 + fr;
    const float wv = wsc[col];
    const float bb = bf16_rne(bias[col]);  // bias.astype(bf16).astype(f32)
#pragma unroll
    for (int m = 0; m < 4; ++m) {
      const int r0 = rbase + m * 16 + hi * 4;
#pragma unroll
      for (int r = 0; r < 4; ++r) {
        const int row = r0 + r;
        // reference order: (acc * act_scale) * w_scale + bias_bf16, then bf16 RNE
        float v = (acc[m][n][r] * asc[row]) * wv + bb;
        out[(size_t)row * N + col] = bf16_rne(v);
      }
    }
  }
}

extern "C" void kernel_launch(void* const* d_in, const int* in_sizes, int n_in,
                              void* d_out, int out_size, void* d_ws, size_t ws_size,
                              hipStream_t stream) {
  const float* x = (const float*)d_in[0];     // [B,S,K] f32
  const float* w = (const float*)d_in[1];     // [N,K] f32
  const float* bias = (const float*)d_in[2];  // [N] f32
  float* out = (float*)d_out;                 // [M,N] f32 (bf16-rounded values)

  const int N = in_sizes[2];             // 4096 (D_OUT)
  const int K = in_sizes[1] / N;         // 4096 (D_IN)
  const int M = in_sizes[0] / K;         // 8192 tokens

  uint8_t* x8 = (uint8_t*)d_ws;                    // M*K bytes
  uint8_t* w8 = x8 + (size_t)M * K;                // N*K bytes
  float* asc = (float*)(w8 + (size_t)N * K);       // M floats
  float* wsc = asc + M;                            // N floats
  (void)ws_size; (void)n_in; (void)out_size;

  quant_rows_kernel<false><<<M, 256, 0, stream>>>(x, x8, asc, K);
  quant_rows_kernel<true><<<N, 256, 0, stream>>>(w, w8, wsc, K);
  gemm_fp8_kernel<<<(M / BM) * (N / BN), 256, 0, stream>>>(x8, w8, asc, wsc, bias, out, M, N, K);
}

// Round 3
// 267.657 us; speedup vs baseline: 2.0614x; 1.6279x over previous
//
#include <hip/hip_runtime.h>
#include <hip/hip_fp16.h>
#include <stdint.h>

#define FP8_MAX_V 448.0f
#define BM 128
#define BN 128
#define BKB 128  // K-bytes per tile step (fp8 => 128 elements); LDS row = 128 B

typedef float floatx4 __attribute__((ext_vector_type(4)));

// Deterministic bf16 round-to-nearest-even of an fp32 value, returned widened to fp32.
__device__ __forceinline__ float bf16_rne(float v) {
  uint32_t u = __float_as_uint(v);
  u = (u + 0x7fffu + ((u >> 16) & 1u)) & 0xffff0000u;
  return __uint_as_float(u);
}

// Pack 4 fp32 (already clipped to +-448) into 4 OCP e4m3fn bytes via HW RNE cvt.
__device__ __forceinline__ uint32_t pack4_fp8(float a, float b, float c, float d) {
  int p = 0;
  p = __builtin_amdgcn_cvt_pk_fp8_f32(a, b, p, false);  // bytes 0..1
  p = __builtin_amdgcn_cvt_pk_fp8_f32(c, d, p, true);   // bytes 2..3
  return (uint32_t)p;
}

__device__ __forceinline__ void gload_lds16(const uint8_t* g, uint8_t* l) {
  __builtin_amdgcn_global_load_lds(
      (const __attribute__((address_space(1))) uint32_t*)g,
      (__attribute__((address_space(3))) uint32_t*)l,
      16, 0, 0);
}

// Per-row quantization: amax over K -> scale -> fp8. FP16RT: fp16 round-trip the
// scale (weight path, matches reference's scale.astype(fp16).astype(fp32)).
template <bool FP16RT>
__global__ __launch_bounds__(256) void quant_rows_kernel(
    const float* __restrict__ in, uint8_t* __restrict__ out8,
    float* __restrict__ scales, int K) {
  const int row = blockIdx.x;
  const int tid = threadIdx.x;
  const float* rp = in + (size_t)row * K;

  // K = 4096: 16 floats/thread as 4x float4, coalesced (stride-256 float4s).
  float4 v[4];
  float amax = 0.f;
#pragma unroll
  for (int i = 0; i < 4; ++i) {
    v[i] = ((const float4*)rp)[i * 256 + tid];
    amax = fmaxf(amax, fmaxf(fmaxf(fabsf(v[i].x), fabsf(v[i].y)),
                             fmaxf(fabsf(v[i].z), fabsf(v[i].w))));
  }
#pragma unroll
  for (int off = 32; off; off >>= 1) amax = fmaxf(amax, __shfl_xor(amax, off));
  __shared__ float red[4];
  if ((tid & 63) == 0) red[tid >> 6] = amax;
  __syncthreads();
  amax = fmaxf(fmaxf(red[0], red[1]), fmaxf(red[2], red[3]));

  float scale = fmaxf(amax / FP8_MAX_V, 1e-6f);
  if (FP16RT) scale = __half2float(__float2half(scale));  // RNE, matches jnp fp16 round-trip
  if (tid == 0) scales[row] = scale;

  uint32_t* op = (uint32_t*)(out8 + (size_t)row * K);
#pragma unroll
  for (int i = 0; i < 4; ++i) {
    // true fp32 division (correctly rounded) to match numpy's x / scale
    float qa = fminf(fmaxf(v[i].x / scale, -FP8_MAX_V), FP8_MAX_V);
    float qb = fminf(fmaxf(v[i].y / scale, -FP8_MAX_V), FP8_MAX_V);
    float qc = fminf(fmaxf(v[i].z / scale, -FP8_MAX_V), FP8_MAX_V);
    float qd = fminf(fmaxf(v[i].w / scale, -FP8_MAX_V), FP8_MAX_V);
    op[i * 256 + tid] = pack4_fp8(qa, qb, qc, qd);
  }
}

// C[t,o] = sum_k A8[t,k]*B8[o,k]  (both K-major), scaled + bias + bf16 round.
// 128x128 tile, BKB=128 bytes, global_load_lds width=16, 4 waves in 2x2,
// each wave 64x64 = 4x4 fragments of 16x16x32 fp8 MFMA, 4 K-steps per tile.
//
// T3-minimum 2-phase pipeline: double-buffered LDS; the NEXT tile's 8
// global_load_lds are issued BEFORE computing the current tile, so HBM/L2
// latency hides under the 64 MFMAs. One vmcnt(0)-draining barrier per tile.
//
// LDS swizzle (T2, rule #21 both-sides): 16B chunk index c16 within each
// 128B row is XOR'd with (row&7). Staging keeps LDS dest linear (gload_lds
// requirement) and pre-swizzles the per-lane GLOBAL source; reads apply the
// same XOR. Bank spread: (4*(c16^(fr&7)) + 2b) mod 32 -> 2-way (free).
__global__ __launch_bounds__(256) void gemm_fp8_kernel(
    const uint8_t* __restrict__ A8, const uint8_t* __restrict__ B8,
    const float* __restrict__ asc, const float* __restrict__ wsc,
    const float* __restrict__ bias, float* __restrict__ out,
    int M, int N, int K) {
  __shared__ __align__(16) uint8_t As[2][BM * BKB];  // 2 x 16 KB
  __shared__ __align__(16) uint8_t Bs[2][BN * BKB];  // 2 x 16 KB

  const int tid = threadIdx.x;
  const int lane = tid & 63;
  const int wid = tid >> 6;
  const int wr = wid >> 1;  // 0..1
  const int wc = wid & 1;   // 0..1

  const int ntn = N / BN;
  const int bm = blockIdx.x / ntn;
  const int bn = blockIdx.x % ntn;

  floatx4 acc[4][4] = {};

  // Staging: thread tid -> LDS linear offset tid*16 (row=tid>>3, c16_phys=tid&7),
  // global source chunk = c16_phys ^ (row&7). Row stride 32 between the 4 calls
  // preserves (row&7), so one source offset serves all calls.
  const int srow = tid >> 3;                      // 0..31
  const int sc_log = (tid & 7) ^ (srow & 7);      // pre-swizzled source chunk
  const uint8_t* ga0 = A8 + (size_t)(bm * BM + srow) * K + sc_log * 16;
  const uint8_t* gb0 = B8 + (size_t)(bn * BN + srow) * K + sc_log * 16;
  const size_t rstep = (size_t)32 * K;

  const int fr = lane & 15;        // fragment row/col within 16
  const int hi = lane >> 4;        // K sub-chunk selector
  const int bofs = (hi & 1) * 8;   // byte offset within 16B chunk
  const int hb = hi >> 1;
  const int fsw = fr & 7;          // read-side swizzle key

  // Stage one K-tile (8 x 16B per thread) into buffer `buf` at K offset k0.
  auto stage = [&](int buf, int k0) {
    uint8_t* lA = As[buf] + tid * 16;
    uint8_t* lB = Bs[buf] + tid * 16;
#pragma unroll
    for (int i = 0; i < 4; ++i) gload_lds16(ga0 + i * rstep + k0, lA + i * 4096);
#pragma unroll
    for (int i = 0; i < 4; ++i) gload_lds16(gb0 + i * rstep + k0, lB + i * 4096);
  };

  const int NT = K / BKB;  // 32
  stage(0, 0);
  __syncthreads();  // drains vmcnt(0) before first compute

  for (int t = 0; t < NT; ++t) {
    const int cur = t & 1;
    if (t + 1 < NT) stage(cur ^ 1, (t + 1) * BKB);  // prefetch next tile FIRST
    __builtin_amdgcn_sched_barrier(0);              // pin issue-before-compute

    const uint8_t* Ab = As[cur];
    const uint8_t* Bb = Bs[cur];
#pragma unroll
    for (int ks = 0; ks < 4; ++ks) {
      const int koff = ((ks * 2 + hb) ^ fsw) * 16 + bofs;  // swizzled read offset
      int64_t a[4], b[4];
#pragma unroll
      for (int m = 0; m < 4; ++m)
        a[m] = *(const int64_t*)(Ab + (size_t)(wr * 64 + m * 16 + fr) * BKB + koff);
#pragma unroll
      for (int n = 0; n < 4; ++n)
        b[n] = *(const int64_t*)(Bb + (size_t)(wc * 64 + n * 16 + fr) * BKB + koff);
#pragma unroll
      for (int m = 0; m < 4; ++m)
#pragma unroll
        for (int n = 0; n < 4; ++n)
          acc[m][n] = __builtin_amdgcn_mfma_f32_16x16x32_fp8_fp8(a[m], b[n], acc[m][n], 0, 0, 0);
    }
    __syncthreads();  // drains vmcnt(0) (prefetch landed) + lgkm; tile boundary
  }

  // Epilogue: C/D 16x16 layout col=lane&15, row=(lane>>4)*4+r (dtype-independent).
  const int rbase = bm * BM + wr * 64;
  const int cbase = bn * BN + wc * 64;
#pragma unroll
  for (int n = 0; n < 4; ++n) {
    const int col = cbase + n * 16 + fr;
    const float wv = wsc[col];
    const float bb = bf16_rne(bias[col]);  // bias.astype(bf16).astype(f32)
#pragma unroll
    for (int m = 0; m < 4; ++m) {
      const int r0 = rbase + m * 16 + hi * 4;
#pragma unroll
      for (int r = 0; r < 4; ++r) {
        const int row = r0 + r;
        // reference order: (acc * act_scale) * w_scale + bias_bf16, then bf16 RNE
        float v = (acc[m][n][r] * asc[row]) * wv + bb;
        out[(size_t)row * N + col] = bf16_rne(v);
      }
    }
  }
}

extern "C" void kernel_launch(void* const* d_in, const int* in_sizes, int n_in,
                              void* d_out, int out_size, void* d_ws, size_t ws_size,
                              hipStream_t stream) {
  const float* x = (const float*)d_in[0];     // [B,S,K] f32
  const float* w = (const float*)d_in[1];     // [N,K] f32
  const float* bias = (const float*)d_in[2];  // [N] f32
  float* out = (float*)d_out;                 // [M,N] f32 (bf16-rounded values)

  const int N = in_sizes[2];             // 4096 (D_OUT)
  const int K = in_sizes[1] / N;         // 4096 (D_IN)
  const int M = in_sizes[0] / K;         // 8192 tokens

  uint8_t* x8 = (uint8_t*)d_ws;                    // M*K bytes
  uint8_t* w8 = x8 + (size_t)M * K;                // N*K bytes
  float* asc = (float*)(w8 + (size_t)N * K);       // M floats
  float* wsc = asc + M;                            // N floats
  (void)ws_size; (void)n_in; (void)out_size;

  quant_rows_kernel<false><<<M, 256, 0, stream>>>(x, x8, asc, K);
  quant_rows_kernel<true><<<N, 256, 0, stream>>>(w, w8, wsc, K);
  gemm_fp8_kernel<<<(M / BM) * (N / BN), 256, 0, stream>>>(x8, w8, asc, wsc, bias, out, M, N, K);
}